// Round 1
// baseline (52.999 us; speedup 1.0000x reference)
//
#include <hip/hip_runtime.h>

// ---------------------------------------------------------------------------
// Kernel 1: precompute A_q = Re(V^dag Z_q V) from qparams.
// V is the fixed 16x16 unitary of the 3 parameterized layers (RX,RY,RZ per
// qubit + CNOT ring). Column j of V = circuit applied to basis state e_j.
// Output: packed upper-triangular (i<=j), off-diag scaled by 2, as float4
// over q: AA[p*4+q], p = 15*i - i*(i-1)/2 + j, 136 pairs -> 544 floats in ws.
// Qubit q maps to bit (3-q) of the flat index (mask 8>>q).
// ---------------------------------------------------------------------------
__global__ __launch_bounds__(256) void qprep_kernel(const float* __restrict__ qp,
                                                    float* __restrict__ AA) {
  __shared__ float Sr[16][16];  // [column][amplitude]
  __shared__ float Si[16][16];
  __shared__ float csc[36], css[36];
  const int t = threadIdx.x;
  if (t < 36) {  // qp is (3,4,3): g = l*12 + q*3 + r
    float th = 0.5f * qp[t];
    csc[t] = cosf(th);
    css[t] = sinf(th);
  }
  Sr[t >> 4][t & 15] = ((t >> 4) == (t & 15)) ? 1.f : 0.f;
  Si[t >> 4][t & 15] = 0.f;
  __syncthreads();

  const int col = t >> 3, pp = t & 7;
  for (int l = 0; l < 3; ++l) {
    for (int q = 0; q < 4; ++q) {
      const int m = 8 >> q;
      for (int r = 0; r < 3; ++r) {
        if (t < 128) {  // 16 columns x 8 amplitude pairs
          const float c = csc[l * 12 + q * 3 + r];
          const float s = css[l * 12 + q * 3 + r];
          const int k = ((pp & ~(m - 1)) << 1) | (pp & (m - 1));  // bit m == 0
          const int k1 = k | m;
          float a0r = Sr[col][k],  a0i = Si[col][k];
          float a1r = Sr[col][k1], a1i = Si[col][k1];
          float n0r, n0i, n1r, n1i;
          if (r == 0) {         // RX: [[c, -i s],[-i s, c]]
            n0r = c * a0r + s * a1i;  n0i = c * a0i - s * a1r;
            n1r = c * a1r + s * a0i;  n1i = c * a1i - s * a0r;
          } else if (r == 1) {  // RY: [[c, -s],[s, c]]
            n0r = c * a0r - s * a1r;  n0i = c * a0i - s * a1i;
            n1r = s * a0r + c * a1r;  n1i = s * a0i + c * a1i;
          } else {              // RZ: diag(e^{-i t/2}, e^{+i t/2})
            n0r = c * a0r + s * a0i;  n0i = c * a0i - s * a0r;
            n1r = c * a1r - s * a1i;  n1i = c * a1i + s * a1r;
          }
          Sr[col][k] = n0r;  Si[col][k] = n0i;
          Sr[col][k1] = n1r; Si[col][k1] = n1i;
        }
        __syncthreads();
      }
    }
    // CNOT ring: (0->1),(1->2),(2->3),(3->0)
    for (int e = 0; e < 4; ++e) {
      if (t < 64) {  // 16 columns x 4 swap pairs
        const int c2 = t >> 2, p2 = t & 3;
        const int mc = 8 >> e;
        const int mt = 8 >> ((e + 1) & 3);
        const int rest = 15 & ~(mc | mt);
        const int rl = rest & (-rest);
        const int rh = rest ^ rl;
        const int k = mc | ((p2 & 1) ? rl : 0) | ((p2 & 2) ? rh : 0);  // bit_c=1, bit_t=0
        const int k1 = k | mt;
        float tr = Sr[c2][k]; Sr[c2][k] = Sr[c2][k1]; Sr[c2][k1] = tr;
        float ti = Si[c2][k]; Si[c2][k] = Si[c2][k1]; Si[c2][k1] = ti;
      }
      __syncthreads();
    }
  }

  // A_q[i][j] = sum_k sign_q(k) * (Vr[k][i]Vr[k][j] + Vi[k][i]Vi[k][j])
  const int i = t >> 4, j = t & 15;
  if (j >= i) {
    float a0 = 0.f, a1 = 0.f, a2 = 0.f, a3 = 0.f;
    for (int k = 0; k < 16; ++k) {
      float pr = Sr[i][k] * Sr[j][k] + Si[i][k] * Si[j][k];
      a0 += (k & 8) ? -pr : pr;
      a1 += (k & 4) ? -pr : pr;
      a2 += (k & 2) ? -pr : pr;
      a3 += (k & 1) ? -pr : pr;
    }
    const float sc = (i == j) ? 1.f : 2.f;
    const int p = 15 * i - (i * (i - 1)) / 2 + j;
    AA[p * 4 + 0] = sc * a0;
    AA[p * 4 + 1] = sc * a1;
    AA[p * 4 + 2] = sc * a2;
    AA[p * 4 + 3] = sc * a3;
  }
}

// ---------------------------------------------------------------------------
// Kernel 2: one block per image. Fuses quantum features (quadratic forms),
// feat4, feat8, residual, head GEMV, and log_softmax.
// ---------------------------------------------------------------------------
__global__ __launch_bounds__(256) void qmain_kernel(
    const float* __restrict__ x, const float* __restrict__ AA,
    const float* __restrict__ dw4_w, const float* __restrict__ dw4_b,
    const float* __restrict__ pw4_w, const float* __restrict__ pw4_b,
    const float* __restrict__ dw8_w, const float* __restrict__ dw8_b,
    const float* __restrict__ pw8_w, const float* __restrict__ pw8_b,
    const float* __restrict__ res_w, const float* __restrict__ res_b,
    const float* __restrict__ hw, const float* __restrict__ hb,
    float* __restrict__ out) {
  __shared__ float xs[784];
  __shared__ __align__(16) float As[544];
  __shared__ float outv[2352];   // (14,14,12) flattened, matches head layout
  __shared__ float rsm[784];     // residual per position (196 x 4)
  __shared__ float z4s[196];     // 49 x 4
  __shared__ float z8s[36];      // 9 x 4
  __shared__ float red[40];      // 4 waves x 10 partial logits
  const int b = blockIdx.x, t = threadIdx.x;
  const float* xb = x + b * 784;
#pragma unroll
  for (int it = 0; it < 4; ++it) {
    int idx = t + it * 256;
    if (idx < 784) xs[idx] = xb[idx];
  }
#pragma unroll
  for (int it = 0; it < 3; ++it) {
    int idx = t + it * 256;
    if (idx < 544) As[idx] = AA[idx];
  }
  __syncthreads();

  if (t < 196) {
    // ---- quantum branch + residual for patch (pi,pj) ----
    const int pi = t / 14, pj = t % 14;
    const int base = (2 * pi) * 28 + 2 * pj;
    const float a0 = xs[base], a1 = xs[base + 1];
    const float a2 = xs[base + 28], a3 = xs[base + 29];
    float c0, s0, c1, s1, c2, s2, c3, s3;
    __sincosf(0.5f * a0, &s0, &c0);
    __sincosf(0.5f * a1, &s1, &c1);
    __sincosf(0.5f * a2, &s2, &c2);
    __sincosf(0.5f * a3, &s3, &c3);
    float psi[16];
#pragma unroll
    for (int k = 0; k < 16; ++k)
      psi[k] = ((k & 8) ? s0 : c0) * ((k & 4) ? s1 : c1) *
               ((k & 2) ? s2 : c2) * ((k & 1) ? s3 : c3);
    float e0 = 0.f, e1 = 0.f, e2 = 0.f, e3 = 0.f;
    const float4* A4 = (const float4*)As;
#pragma unroll
    for (int i = 0; i < 16; ++i) {
#pragma unroll
      for (int j = i; j < 16; ++j) {
        const int p = 15 * i - (i * (i - 1)) / 2 + j;
        float4 a = A4[p];                 // uniform across wave -> broadcast
        float w = psi[i] * psi[j];
        e0 += a.x * w; e1 += a.y * w; e2 += a.z * w; e3 += a.w * w;
      }
    }
    const float avg = 0.25f * (a0 + a1 + a2 + a3);
    const float ez[4] = {e0, e1, e2, e3};
#pragma unroll
    for (int c = 0; c < 4; ++c) {
      float r = res_w[c] * avg + res_b[c];
      rsm[t * 4 + c] = r;
      outv[t * 12 + c] = ez[c] + r;
    }
  } else if (t < 245) {
    // ---- feat4: 4x4 stride-4 conv + 1x1 + relu, 49 positions ----
    const int tt = t - 196;
    const int i = tt / 7, j = tt % 7;
    float y[4];
#pragma unroll
    for (int c = 0; c < 4; ++c) y[c] = dw4_b[c];
#pragma unroll
    for (int u = 0; u < 4; ++u)
#pragma unroll
      for (int v = 0; v < 4; ++v) {
        float xv = xs[(4 * i + u) * 28 + 4 * j + v];
#pragma unroll
        for (int c = 0; c < 4; ++c) y[c] += dw4_w[c * 16 + u * 4 + v] * xv;
      }
#pragma unroll
    for (int o = 0; o < 4; ++o) {
      float z = pw4_b[o];
#pragma unroll
      for (int c = 0; c < 4; ++c) z += pw4_w[o * 4 + c] * y[c];
      z4s[tt * 4 + o] = fmaxf(z, 0.f);
    }
  } else if (t < 254) {
    // ---- feat8: 8x8 stride-8 conv + 1x1 + relu, 9 positions ----
    const int tt = t - 245;
    const int i = tt / 3, j = tt % 3;
    float y[4];
#pragma unroll
    for (int c = 0; c < 4; ++c) y[c] = dw8_b[c];
    for (int u = 0; u < 8; ++u)
#pragma unroll
      for (int v = 0; v < 8; ++v) {
        float xv = xs[(8 * i + u) * 28 + 8 * j + v];
#pragma unroll
        for (int c = 0; c < 4; ++c) y[c] += dw8_w[c * 64 + u * 8 + v] * xv;
      }
#pragma unroll
    for (int o = 0; o < 4; ++o) {
      float z = pw8_b[o];
#pragma unroll
      for (int c = 0; c < 4; ++c) z += pw8_w[o * 4 + c] * y[c];
      z8s[tt * 4 + o] = fmaxf(z, 0.f);
    }
  }
  __syncthreads();

  if (t < 196) {
    // ---- upsample feat4 (x2 nearest) and feat8 (3->14 half-pixel nearest) ----
    const int pi = t / 14, pj = t % 14;
    const int q4 = ((pi >> 1) * 7 + (pj >> 1)) * 4;
    const int m8i = (pi < 5) ? 0 : ((pi < 9) ? 1 : 2);
    const int m8j = (pj < 5) ? 0 : ((pj < 9) ? 1 : 2);
    const int q8 = (m8i * 3 + m8j) * 4;
#pragma unroll
    for (int c = 0; c < 4; ++c) {
      float r = rsm[t * 4 + c];
      outv[t * 12 + 4 + c] = z4s[q4 + c] + r;
      outv[t * 12 + 8 + c] = z8s[q8 + c] + r;
    }
  }
  __syncthreads();

  // ---- head GEMV: logits[k] = sum_idx outv[idx] * hw[k*2352+idx] ----
  float acc[10];
#pragma unroll
  for (int k = 0; k < 10; ++k) acc[k] = 0.f;
  for (int idx = t; idx < 2352; idx += 256) {
    float v = outv[idx];
#pragma unroll
    for (int k = 0; k < 10; ++k) acc[k] += v * hw[k * 2352 + idx];
  }
#pragma unroll
  for (int k = 0; k < 10; ++k) {
#pragma unroll
    for (int off = 32; off > 0; off >>= 1) acc[k] += __shfl_xor(acc[k], off);
  }
  const int lane = t & 63, w = t >> 6;
  if (lane == 0) {
#pragma unroll
    for (int k = 0; k < 10; ++k) red[w * 10 + k] = acc[k];
  }
  __syncthreads();
  if (t == 0) {
    float lg[10], m = -1e30f;
#pragma unroll
    for (int k = 0; k < 10; ++k) {
      lg[k] = red[k] + red[10 + k] + red[20 + k] + red[30 + k] + hb[k];
      m = fmaxf(m, lg[k]);
    }
    float se = 0.f;
#pragma unroll
    for (int k = 0; k < 10; ++k) se += __expf(lg[k] - m);
    const float ls = m + __logf(se);
#pragma unroll
    for (int k = 0; k < 10; ++k) out[b * 10 + k] = lg[k] - ls;
  }
}

extern "C" void kernel_launch(void* const* d_in, const int* in_sizes, int n_in,
                              void* d_out, int out_size, void* d_ws, size_t ws_size,
                              hipStream_t stream) {
  const float* x      = (const float*)d_in[0];
  const float* qp     = (const float*)d_in[1];
  const float* dw4_w  = (const float*)d_in[2];
  const float* dw4_b  = (const float*)d_in[3];
  const float* pw4_w  = (const float*)d_in[4];
  const float* pw4_b  = (const float*)d_in[5];
  const float* dw8_w  = (const float*)d_in[6];
  const float* dw8_b  = (const float*)d_in[7];
  const float* pw8_w  = (const float*)d_in[8];
  const float* pw8_b  = (const float*)d_in[9];
  const float* res_w  = (const float*)d_in[10];
  const float* res_b  = (const float*)d_in[11];
  const float* head_w = (const float*)d_in[12];
  const float* head_b = (const float*)d_in[13];
  float* out = (float*)d_out;
  float* AA = (float*)d_ws;  // 544 floats
  const int B = in_sizes[0] / 784;

  hipLaunchKernelGGL(qprep_kernel, dim3(1), dim3(256), 0, stream, qp, AA);
  hipLaunchKernelGGL(qmain_kernel, dim3(B), dim3(256), 0, stream,
                     x, AA, dw4_w, dw4_b, pw4_w, pw4_b, dw8_w, dw8_b,
                     pw8_w, pw8_b, res_w, res_b, head_w, head_b, out);
}

// Round 2
// 40.826 us; speedup vs baseline: 1.2982x; 1.2982x over previous
//
#include <hip/hip_runtime.h>

// ---------------------------------------------------------------------------
// Kernel 1: from qparams build V (16x16 unitary of the 3 parameterized
// layers), then A_q = Re(V^dag Z_q V), then change-of-basis tensor
// T[m0,m1,m2,m3].q  (m in {1, cos, sin} per qubit), 81 float4 = 324 floats.
// E_q(patch) = sum_m T[m].q * prod_t v_t[m_t],  v_t = (1, cos a_t, sin a_t).
// ---------------------------------------------------------------------------
__global__ __launch_bounds__(256) void qprep_kernel(const float* __restrict__ qp,
                                                    float* __restrict__ T) {
  __shared__ float Sr[16][16];  // [column][amplitude]
  __shared__ float Si[16][16];
  __shared__ float csc[36], css[36];
  __shared__ float Afs[256][4];  // A_q[i][j], full symmetric
  const int t = threadIdx.x;
  if (t < 36) {  // qp is (3,4,3): g = l*12 + q*3 + r
    float th = 0.5f * qp[t];
    csc[t] = cosf(th);
    css[t] = sinf(th);
  }
  Sr[t >> 4][t & 15] = ((t >> 4) == (t & 15)) ? 1.f : 0.f;
  Si[t >> 4][t & 15] = 0.f;
  __syncthreads();

  const int col = t >> 3, pp = t & 7;
  for (int l = 0; l < 3; ++l) {
    for (int q = 0; q < 4; ++q) {
      const int m = 8 >> q;
      for (int r = 0; r < 3; ++r) {
        if (t < 128) {  // 16 columns x 8 amplitude pairs
          const float c = csc[l * 12 + q * 3 + r];
          const float s = css[l * 12 + q * 3 + r];
          const int k = ((pp & ~(m - 1)) << 1) | (pp & (m - 1));  // bit m == 0
          const int k1 = k | m;
          float a0r = Sr[col][k],  a0i = Si[col][k];
          float a1r = Sr[col][k1], a1i = Si[col][k1];
          float n0r, n0i, n1r, n1i;
          if (r == 0) {         // RX
            n0r = c * a0r + s * a1i;  n0i = c * a0i - s * a1r;
            n1r = c * a1r + s * a0i;  n1i = c * a1i - s * a0r;
          } else if (r == 1) {  // RY
            n0r = c * a0r - s * a1r;  n0i = c * a0i - s * a1i;
            n1r = s * a0r + c * a1r;  n1i = s * a0i + c * a1i;
          } else {              // RZ
            n0r = c * a0r + s * a0i;  n0i = c * a0i - s * a0r;
            n1r = c * a1r - s * a1i;  n1i = c * a1i + s * a1r;
          }
          Sr[col][k] = n0r;  Si[col][k] = n0i;
          Sr[col][k1] = n1r; Si[col][k1] = n1i;
        }
        __syncthreads();
      }
    }
    // CNOT ring: (0->1),(1->2),(2->3),(3->0)
    for (int e = 0; e < 4; ++e) {
      if (t < 64) {
        const int c2 = t >> 2, p2 = t & 3;
        const int mc = 8 >> e;
        const int mt = 8 >> ((e + 1) & 3);
        const int rest = 15 & ~(mc | mt);
        const int rl = rest & (-rest);
        const int rh = rest ^ rl;
        const int k = mc | ((p2 & 1) ? rl : 0) | ((p2 & 2) ? rh : 0);
        const int k1 = k | mt;
        float tr = Sr[c2][k]; Sr[c2][k] = Sr[c2][k1]; Sr[c2][k1] = tr;
        float ti = Si[c2][k]; Si[c2][k] = Si[c2][k1]; Si[c2][k1] = ti;
      }
      __syncthreads();
    }
  }

  // A_q[i][j] = sum_k sign_q(k) * (V[k][i]V[k][j] re+im);  V[k][i] = Sr[i][k]
  {
    const int i = t >> 4, j = t & 15;
    float a0 = 0.f, a1 = 0.f, a2 = 0.f, a3 = 0.f;
    for (int k = 0; k < 16; ++k) {
      float pr = Sr[i][k] * Sr[j][k] + Si[i][k] * Si[j][k];
      a0 += (k & 8) ? -pr : pr;
      a1 += (k & 4) ? -pr : pr;
      a2 += (k & 2) ? -pr : pr;
      a3 += (k & 1) ? -pr : pr;
    }
    Afs[t][0] = a0; Afs[t][1] = a1; Afs[t][2] = a2; Afs[t][3] = a3;
  }
  __syncthreads();

  // T[mi].q = (1/16) * sum over 16 per-qubit choices of +-A[i][j]
  for (int o = t; o < 324; o += 256) {
    const int mi = o >> 2, q = o & 3;
    const int m0 = mi / 27, m1 = (mi / 9) % 3, m2 = (mi / 3) % 3, m3 = mi % 3;
    const int mm[4] = {m0, m1, m2, m3};
    float acc = 0.f;
    for (int c = 0; c < 16; ++c) {
      int ii = 0, jj = 0; float sg = 1.f;
      for (int qb = 0; qb < 4; ++qb) {
        const int cb = (c >> qb) & 1, bit = 8 >> qb, mq = mm[qb];
        if (mq == 2) { if (cb) ii |= bit; else jj |= bit; }
        else if (cb) { ii |= bit; jj |= bit; if (mq == 1) sg = -sg; }
      }
      acc += sg * Afs[ii * 16 + jj][q];
    }
    T[mi * 4 + q] = acc * 0.0625f;
  }
}

// ---------------------------------------------------------------------------
// Kernel 2: one block per image.
// ---------------------------------------------------------------------------
__global__ __launch_bounds__(256) void qmain_kernel(
    const float* __restrict__ x, const float4* __restrict__ T4,
    const float* __restrict__ dw4_w, const float* __restrict__ dw4_b,
    const float* __restrict__ pw4_w, const float* __restrict__ pw4_b,
    const float* __restrict__ dw8_w, const float* __restrict__ dw8_b,
    const float* __restrict__ pw8_w, const float* __restrict__ pw8_b,
    const float* __restrict__ res_w, const float* __restrict__ res_b,
    const float* __restrict__ hw, const float* __restrict__ hb,
    float* __restrict__ out) {
  __shared__ __align__(16) float xs[784];
  __shared__ __align__(16) float outv[2352];  // (14,14,12)
  __shared__ float z4s[196];                  // 49 x 4 (post pw4+relu)
  __shared__ float z8d[36];                   // 9 x 4 (dw8 only)
  __shared__ float z8s[36];                   // 9 x 4 (post pw8+relu)
  __shared__ float red[40];
  const int b = blockIdx.x, t = threadIdx.x;
  const float4* xs4 = (const float4*)xs;

  if (t < 196) ((float4*)xs)[t] = ((const float4*)(x + b * 784))[t];
  __syncthreads();

  float4 e = {0.f, 0.f, 0.f, 0.f};
  float r0 = 0.f, r1 = 0.f, r2 = 0.f, r3 = 0.f;
  const bool isq = (t < 196);
  if (isq) {
    // ---- quantum branch (trig-basis Horner) + residual ----
    const int pi = t / 14, pj = t % 14;
    const int base = (2 * pi) * 28 + 2 * pj;
    const float a0 = xs[base], a1 = xs[base + 1];
    const float a2 = xs[base + 28], a3 = xs[base + 29];
    float ca[4], sa[4];
    __sincosf(a0, &sa[0], &ca[0]);
    __sincosf(a1, &sa[1], &ca[1]);
    __sincosf(a2, &sa[2], &ca[2]);
    __sincosf(a3, &sa[3], &ca[3]);
#pragma unroll
    for (int m0 = 0; m0 < 3; ++m0) {
      float4 c1 = {0.f, 0.f, 0.f, 0.f};
#pragma unroll
      for (int m1 = 0; m1 < 3; ++m1) {
        float4 c2 = {0.f, 0.f, 0.f, 0.f};
#pragma unroll
        for (int m2 = 0; m2 < 3; ++m2) {
          const int bi = m0 * 27 + m1 * 9 + m2 * 3;
          const float4 t0 = T4[bi], t1 = T4[bi + 1], t2 = T4[bi + 2];
          float4 a3v;
          a3v.x = fmaf(t2.x, sa[3], fmaf(t1.x, ca[3], t0.x));
          a3v.y = fmaf(t2.y, sa[3], fmaf(t1.y, ca[3], t0.y));
          a3v.z = fmaf(t2.z, sa[3], fmaf(t1.z, ca[3], t0.z));
          a3v.w = fmaf(t2.w, sa[3], fmaf(t1.w, ca[3], t0.w));
          const float f2 = (m2 == 0) ? 1.f : ((m2 == 1) ? ca[2] : sa[2]);
          c2.x = fmaf(a3v.x, f2, c2.x);
          c2.y = fmaf(a3v.y, f2, c2.y);
          c2.z = fmaf(a3v.z, f2, c2.z);
          c2.w = fmaf(a3v.w, f2, c2.w);
        }
        const float f1 = (m1 == 0) ? 1.f : ((m1 == 1) ? ca[1] : sa[1]);
        c1.x = fmaf(c2.x, f1, c1.x);
        c1.y = fmaf(c2.y, f1, c1.y);
        c1.z = fmaf(c2.z, f1, c1.z);
        c1.w = fmaf(c2.w, f1, c1.w);
      }
      const float f0 = (m0 == 0) ? 1.f : ((m0 == 1) ? ca[0] : sa[0]);
      e.x = fmaf(c1.x, f0, e.x);
      e.y = fmaf(c1.y, f0, e.y);
      e.z = fmaf(c1.z, f0, e.z);
      e.w = fmaf(c1.w, f0, e.w);
    }
    const float avg = 0.25f * (a0 + a1 + a2 + a3);
    r0 = fmaf(res_w[0], avg, res_b[0]);
    r1 = fmaf(res_w[1], avg, res_b[1]);
    r2 = fmaf(res_w[2], avg, res_b[2]);
    r3 = fmaf(res_w[3], avg, res_b[3]);
  }
  if (t < 36) {
    // ---- feat8 depthwise 8x8 stride 8 (one (pos,ch) per thread) ----
    const int pos = t >> 2, ch = t & 3;
    const int i8 = pos / 3, j8 = pos % 3;
    const float4* w84 = (const float4*)dw8_w;
    float4 acc = {0.f, 0.f, 0.f, 0.f};
#pragma unroll
    for (int u = 0; u < 8; ++u) {
      const float4 xa = xs4[(8 * i8 + u) * 7 + 2 * j8];
      const float4 xb2 = xs4[(8 * i8 + u) * 7 + 2 * j8 + 1];
      const float4 wa = w84[ch * 16 + u * 2];
      const float4 wb = w84[ch * 16 + u * 2 + 1];
      acc.x = fmaf(wa.x, xa.x, acc.x); acc.y = fmaf(wa.y, xa.y, acc.y);
      acc.z = fmaf(wa.z, xa.z, acc.z); acc.w = fmaf(wa.w, xa.w, acc.w);
      acc.x = fmaf(wb.x, xb2.x, acc.x); acc.y = fmaf(wb.y, xb2.y, acc.y);
      acc.z = fmaf(wb.z, xb2.z, acc.z); acc.w = fmaf(wb.w, xb2.w, acc.w);
    }
    z8d[t] = acc.x + acc.y + acc.z + acc.w + dw8_b[ch];
  }
  if (t >= 196 && t < 245) {
    // ---- feat4: 4x4 stride-4 dw + 1x1 + relu ----
    const int tt = t - 196;
    const int i = tt / 7, j = tt % 7;
    const float4* w44 = (const float4*)dw4_w;
    float y[4];
#pragma unroll
    for (int c = 0; c < 4; ++c) {
      float4 acc = {0.f, 0.f, 0.f, 0.f};
#pragma unroll
      for (int u = 0; u < 4; ++u) {
        const float4 xa = xs4[(4 * i + u) * 7 + j];
        const float4 wa = w44[c * 4 + u];
        acc.x = fmaf(wa.x, xa.x, acc.x); acc.y = fmaf(wa.y, xa.y, acc.y);
        acc.z = fmaf(wa.z, xa.z, acc.z); acc.w = fmaf(wa.w, xa.w, acc.w);
      }
      y[c] = acc.x + acc.y + acc.z + acc.w + dw4_b[c];
    }
#pragma unroll
    for (int o = 0; o < 4; ++o) {
      float z = pw4_b[o];
#pragma unroll
      for (int c = 0; c < 4; ++c) z = fmaf(pw4_w[o * 4 + c], y[c], z);
      z4s[tt * 4 + o] = fmaxf(z, 0.f);
    }
  }
  __syncthreads();

  if (t < 9) {
    // ---- pw8 + relu ----
    float yv[4];
#pragma unroll
    for (int c = 0; c < 4; ++c) yv[c] = z8d[t * 4 + c];
#pragma unroll
    for (int o = 0; o < 4; ++o) {
      float z = pw8_b[o];
#pragma unroll
      for (int c = 0; c < 4; ++c) z = fmaf(pw8_w[o * 4 + c], yv[c], z);
      z8s[t * 4 + o] = fmaxf(z, 0.f);
    }
  }
  __syncthreads();

  if (isq) {
    // ---- assemble 12 output channels for this position ----
    const int pi = t / 14, pj = t % 14;
    const int q4 = ((pi >> 1) * 7 + (pj >> 1)) * 4;
    const int m8i = (pi < 5) ? 0 : ((pi < 9) ? 1 : 2);
    const int m8j = (pj < 5) ? 0 : ((pj < 9) ? 1 : 2);
    const int q8 = (m8i * 3 + m8j) * 4;
    outv[t * 12 + 0] = e.x + r0;
    outv[t * 12 + 1] = e.y + r1;
    outv[t * 12 + 2] = e.z + r2;
    outv[t * 12 + 3] = e.w + r3;
    outv[t * 12 + 4] = z4s[q4 + 0] + r0;
    outv[t * 12 + 5] = z4s[q4 + 1] + r1;
    outv[t * 12 + 6] = z4s[q4 + 2] + r2;
    outv[t * 12 + 7] = z4s[q4 + 3] + r3;
    outv[t * 12 + 8]  = z8s[q8 + 0] + r0;
    outv[t * 12 + 9]  = z8s[q8 + 1] + r1;
    outv[t * 12 + 10] = z8s[q8 + 2] + r2;
    outv[t * 12 + 11] = z8s[q8 + 3] + r3;
  }
  __syncthreads();

  // ---- head GEMV (float4) ----
  const float4* outv4 = (const float4*)outv;
  const float4* hw4 = (const float4*)hw;
  float acc[10];
#pragma unroll
  for (int k = 0; k < 10; ++k) acc[k] = 0.f;
#pragma unroll
  for (int it = 0; it < 3; ++it) {
    const int idx = t + it * 256;
    if (idx < 588) {
      const float4 v = outv4[idx];
#pragma unroll
      for (int k = 0; k < 10; ++k) {
        const float4 w = hw4[k * 588 + idx];
        acc[k] = fmaf(v.x, w.x, acc[k]);
        acc[k] = fmaf(v.y, w.y, acc[k]);
        acc[k] = fmaf(v.z, w.z, acc[k]);
        acc[k] = fmaf(v.w, w.w, acc[k]);
      }
    }
  }
#pragma unroll
  for (int k = 0; k < 10; ++k) {
#pragma unroll
    for (int off = 32; off > 0; off >>= 1) acc[k] += __shfl_xor(acc[k], off);
  }
  const int lane = t & 63, w = t >> 6;
  if (lane == 0) {
#pragma unroll
    for (int k = 0; k < 10; ++k) red[w * 10 + k] = acc[k];
  }
  __syncthreads();
  if (t == 0) {
    float lg[10], m = -1e30f;
#pragma unroll
    for (int k = 0; k < 10; ++k) {
      lg[k] = red[k] + red[10 + k] + red[20 + k] + red[30 + k] + hb[k];
      m = fmaxf(m, lg[k]);
    }
    float se = 0.f;
#pragma unroll
    for (int k = 0; k < 10; ++k) se += __expf(lg[k] - m);
    const float ls = m + __logf(se);
#pragma unroll
    for (int k = 0; k < 10; ++k) out[b * 10 + k] = lg[k] - ls;
  }
}

extern "C" void kernel_launch(void* const* d_in, const int* in_sizes, int n_in,
                              void* d_out, int out_size, void* d_ws, size_t ws_size,
                              hipStream_t stream) {
  const float* x      = (const float*)d_in[0];
  const float* qp     = (const float*)d_in[1];
  const float* dw4_w  = (const float*)d_in[2];
  const float* dw4_b  = (const float*)d_in[3];
  const float* pw4_w  = (const float*)d_in[4];
  const float* pw4_b  = (const float*)d_in[5];
  const float* dw8_w  = (const float*)d_in[6];
  const float* dw8_b  = (const float*)d_in[7];
  const float* pw8_w  = (const float*)d_in[8];
  const float* pw8_b  = (const float*)d_in[9];
  const float* res_w  = (const float*)d_in[10];
  const float* res_b  = (const float*)d_in[11];
  const float* head_w = (const float*)d_in[12];
  const float* head_b = (const float*)d_in[13];
  float* out = (float*)d_out;
  float* T = (float*)d_ws;  // 324 floats
  const int B = in_sizes[0] / 784;

  hipLaunchKernelGGL(qprep_kernel, dim3(1), dim3(256), 0, stream, qp, T);
  hipLaunchKernelGGL(qmain_kernel, dim3(B), dim3(256), 0, stream,
                     x, (const float4*)T, dw4_w, dw4_b, pw4_w, pw4_b,
                     dw8_w, dw8_b, pw8_w, pw8_b, res_w, res_b,
                     head_w, head_b, out);
}

// Round 3
// 39.903 us; speedup vs baseline: 1.3282x; 1.0231x over previous
//
#include <hip/hip_runtime.h>

// ws layout (float offsets)
#define WS_T    0      // 324 floats: trig-basis tensor T[81][4]
#define WS_HQ   512    // 7840: hwq[k][pos] as float4 (quantum head weights)
#define WS_WA   8352   // 1960: wavg[k][pos] (residual-avg head weights)
#define WS_H4   10312  // 1960: hz4[k][p4] as float4
#define WS_H8   12272  // 360:  hz8[k][p8] as float4
#define WS_C10  12632  // 10:   per-class constant (hb + res_b terms)

// ---------------------------------------------------------------------------
// Prep kernel, grid = 11 blocks.
// Blocks 0..9: fold head weights for class k into branch-reduced forms.
// Block 10: build V (16x16 unitary of the parameterized layers), then
// A_q = Re(V^dag Z_q V), then the trig-basis tensor T.
// ---------------------------------------------------------------------------
__global__ __launch_bounds__(256) void prep_kernel(
    const float* __restrict__ qp, const float* __restrict__ hw,
    const float* __restrict__ res_w, const float* __restrict__ res_b,
    const float* __restrict__ hb, float* __restrict__ ws) {
  __shared__ float row[2352];
  __shared__ float cred[4];
  __shared__ float Sr[16][16];
  __shared__ float Si[16][16];
  __shared__ float csc[36], css[36];
  __shared__ float Afs[256][4];
  const int t = threadIdx.x;

  if (blockIdx.x < 10) {
    const int k = blockIdx.x;
    for (int i = t; i < 2352; i += 256) row[i] = hw[k * 2352 + i];
    __syncthreads();
    float cpart = 0.f;
    if (t < 196) {
      const int b12 = t * 12;
      float4 h = {row[b12], row[b12 + 1], row[b12 + 2], row[b12 + 3]};
      ((float4*)(ws + WS_HQ))[k * 196 + t] = h;
      float wa = 0.f;
#pragma unroll
      for (int c = 0; c < 4; ++c) {
        const float s3 = row[b12 + c] + row[b12 + 4 + c] + row[b12 + 8 + c];
        wa += res_w[c] * s3;
        cpart += res_b[c] * s3;
      }
      ws[WS_WA + k * 196 + t] = wa;
    }
    if (t < 49) {
      const int i4 = t / 7, j4 = t % 7;
      float4 s = {0.f, 0.f, 0.f, 0.f};
#pragma unroll
      for (int di = 0; di < 2; ++di)
#pragma unroll
        for (int dj = 0; dj < 2; ++dj) {
          const int pos = (2 * i4 + di) * 14 + 2 * j4 + dj;
          s.x += row[pos * 12 + 4]; s.y += row[pos * 12 + 5];
          s.z += row[pos * 12 + 6]; s.w += row[pos * 12 + 7];
        }
      ((float4*)(ws + WS_H4))[k * 49 + t] = s;
    }
    if (t < 9) {
      const int i8 = t / 3, j8 = t % 3;
      const int pi0 = (i8 == 0) ? 0 : ((i8 == 1) ? 5 : 9);
      const int pi1 = (i8 == 0) ? 5 : ((i8 == 1) ? 9 : 14);
      const int pj0 = (j8 == 0) ? 0 : ((j8 == 1) ? 5 : 9);
      const int pj1 = (j8 == 0) ? 5 : ((j8 == 1) ? 9 : 14);
      float4 s = {0.f, 0.f, 0.f, 0.f};
      for (int pi = pi0; pi < pi1; ++pi)
        for (int pj = pj0; pj < pj1; ++pj) {
          const int pos = pi * 14 + pj;
          s.x += row[pos * 12 + 8]; s.y += row[pos * 12 + 9];
          s.z += row[pos * 12 + 10]; s.w += row[pos * 12 + 11];
        }
      ((float4*)(ws + WS_H8))[k * 9 + t] = s;
    }
#pragma unroll
    for (int off = 32; off > 0; off >>= 1) cpart += __shfl_xor(cpart, off);
    if ((t & 63) == 0) cred[t >> 6] = cpart;
    __syncthreads();
    if (t == 0) ws[WS_C10 + k] = hb[k] + cred[0] + cred[1] + cred[2] + cred[3];
    return;
  }

  // ---- block 10: quantum tensor T ----
  if (t < 36) {
    float th = 0.5f * qp[t];
    csc[t] = cosf(th);
    css[t] = sinf(th);
  }
  Sr[t >> 4][t & 15] = ((t >> 4) == (t & 15)) ? 1.f : 0.f;
  Si[t >> 4][t & 15] = 0.f;
  __syncthreads();

  const int col = t >> 3, pp = t & 7;
  for (int l = 0; l < 3; ++l) {
    for (int q = 0; q < 4; ++q) {
      const int m = 8 >> q;
      for (int r = 0; r < 3; ++r) {
        if (t < 128) {
          const float c = csc[l * 12 + q * 3 + r];
          const float s = css[l * 12 + q * 3 + r];
          const int k = ((pp & ~(m - 1)) << 1) | (pp & (m - 1));
          const int k1 = k | m;
          float a0r = Sr[col][k],  a0i = Si[col][k];
          float a1r = Sr[col][k1], a1i = Si[col][k1];
          float n0r, n0i, n1r, n1i;
          if (r == 0) {         // RX
            n0r = c * a0r + s * a1i;  n0i = c * a0i - s * a1r;
            n1r = c * a1r + s * a0i;  n1i = c * a1i - s * a0r;
          } else if (r == 1) {  // RY
            n0r = c * a0r - s * a1r;  n0i = c * a0i - s * a1i;
            n1r = s * a0r + c * a1r;  n1i = s * a0i + c * a1i;
          } else {              // RZ
            n0r = c * a0r + s * a0i;  n0i = c * a0i - s * a0r;
            n1r = c * a1r - s * a1i;  n1i = c * a1i + s * a1r;
          }
          Sr[col][k] = n0r;  Si[col][k] = n0i;
          Sr[col][k1] = n1r; Si[col][k1] = n1i;
        }
        __syncthreads();
      }
    }
    for (int e = 0; e < 4; ++e) {
      if (t < 64) {
        const int c2 = t >> 2, p2 = t & 3;
        const int mc = 8 >> e;
        const int mt = 8 >> ((e + 1) & 3);
        const int rest = 15 & ~(mc | mt);
        const int rl = rest & (-rest);
        const int rh = rest ^ rl;
        const int k = mc | ((p2 & 1) ? rl : 0) | ((p2 & 2) ? rh : 0);
        const int k1 = k | mt;
        float tr = Sr[c2][k]; Sr[c2][k] = Sr[c2][k1]; Sr[c2][k1] = tr;
        float ti = Si[c2][k]; Si[c2][k] = Si[c2][k1]; Si[c2][k1] = ti;
      }
      __syncthreads();
    }
  }

  {
    const int i = t >> 4, j = t & 15;
    float a0 = 0.f, a1 = 0.f, a2 = 0.f, a3 = 0.f;
    for (int k = 0; k < 16; ++k) {
      float pr = Sr[i][k] * Sr[j][k] + Si[i][k] * Si[j][k];
      a0 += (k & 8) ? -pr : pr;
      a1 += (k & 4) ? -pr : pr;
      a2 += (k & 2) ? -pr : pr;
      a3 += (k & 1) ? -pr : pr;
    }
    Afs[t][0] = a0; Afs[t][1] = a1; Afs[t][2] = a2; Afs[t][3] = a3;
  }
  __syncthreads();

  for (int o = t; o < 324; o += 256) {
    const int mi = o >> 2, q = o & 3;
    const int m0 = mi / 27, m1 = (mi / 9) % 3, m2 = (mi / 3) % 3, m3 = mi % 3;
    const int mm[4] = {m0, m1, m2, m3};
    float acc = 0.f;
    for (int c = 0; c < 16; ++c) {
      int ii = 0, jj = 0; float sg = 1.f;
      for (int qb = 0; qb < 4; ++qb) {
        const int cb = (c >> qb) & 1, bit = 8 >> qb, mq = mm[qb];
        if (mq == 2) { if (cb) ii |= bit; else jj |= bit; }
        else if (cb) { ii |= bit; jj |= bit; if (mq == 1) sg = -sg; }
      }
      acc += sg * Afs[ii * 16 + jj][q];
    }
    ws[WS_T + mi * 4 + q] = acc * 0.0625f;
  }
}

// ---------------------------------------------------------------------------
// Main kernel: one block per image; every thread accumulates its feature's
// contribution directly into the 10 logits.
// ---------------------------------------------------------------------------
__global__ __launch_bounds__(256) void qmain_kernel(
    const float* __restrict__ x, const float4* __restrict__ T4,
    const float4* __restrict__ HQ4, const float* __restrict__ WA,
    const float4* __restrict__ H44, const float4* __restrict__ H84,
    const float* __restrict__ C10,
    const float* __restrict__ dw4_w, const float* __restrict__ dw4_b,
    const float* __restrict__ pw4_w, const float* __restrict__ pw4_b,
    const float* __restrict__ dw8_w, const float* __restrict__ dw8_b,
    const float* __restrict__ pw8_w, const float* __restrict__ pw8_b,
    float* __restrict__ out) {
  __shared__ __align__(16) float xs[784];
  __shared__ float z8d[36];
  __shared__ float red[40];
  const int b = blockIdx.x, t = threadIdx.x;
  const float4* xs4 = (const float4*)xs;

  if (t < 196) ((float4*)xs)[t] = ((const float4*)(x + b * 784))[t];
  __syncthreads();

  float acc[10];
#pragma unroll
  for (int k = 0; k < 10; ++k) acc[k] = 0.f;

  if (t < 196) {
    // ---- quantum feature (trig-basis Horner) + residual-avg, dot into acc --
    const int pi = t / 14, pj = t % 14;
    const int base = (2 * pi) * 28 + 2 * pj;
    const float a0 = xs[base], a1 = xs[base + 1];
    const float a2 = xs[base + 28], a3 = xs[base + 29];
    float ca[4], sa[4];
    __sincosf(a0, &sa[0], &ca[0]);
    __sincosf(a1, &sa[1], &ca[1]);
    __sincosf(a2, &sa[2], &ca[2]);
    __sincosf(a3, &sa[3], &ca[3]);
    float4 e = {0.f, 0.f, 0.f, 0.f};
#pragma unroll
    for (int m0 = 0; m0 < 3; ++m0) {
      float4 c1 = {0.f, 0.f, 0.f, 0.f};
#pragma unroll
      for (int m1 = 0; m1 < 3; ++m1) {
        float4 c2 = {0.f, 0.f, 0.f, 0.f};
#pragma unroll
        for (int m2 = 0; m2 < 3; ++m2) {
          const int bi = m0 * 27 + m1 * 9 + m2 * 3;
          const float4 t0 = T4[bi], t1 = T4[bi + 1], t2 = T4[bi + 2];
          float4 a3v;
          a3v.x = fmaf(t2.x, sa[3], fmaf(t1.x, ca[3], t0.x));
          a3v.y = fmaf(t2.y, sa[3], fmaf(t1.y, ca[3], t0.y));
          a3v.z = fmaf(t2.z, sa[3], fmaf(t1.z, ca[3], t0.z));
          a3v.w = fmaf(t2.w, sa[3], fmaf(t1.w, ca[3], t0.w));
          const float f2 = (m2 == 0) ? 1.f : ((m2 == 1) ? ca[2] : sa[2]);
          c2.x = fmaf(a3v.x, f2, c2.x);
          c2.y = fmaf(a3v.y, f2, c2.y);
          c2.z = fmaf(a3v.z, f2, c2.z);
          c2.w = fmaf(a3v.w, f2, c2.w);
        }
        const float f1 = (m1 == 0) ? 1.f : ((m1 == 1) ? ca[1] : sa[1]);
        c1.x = fmaf(c2.x, f1, c1.x);
        c1.y = fmaf(c2.y, f1, c1.y);
        c1.z = fmaf(c2.z, f1, c1.z);
        c1.w = fmaf(c2.w, f1, c1.w);
      }
      const float f0 = (m0 == 0) ? 1.f : ((m0 == 1) ? ca[0] : sa[0]);
      e.x = fmaf(c1.x, f0, e.x);
      e.y = fmaf(c1.y, f0, e.y);
      e.z = fmaf(c1.z, f0, e.z);
      e.w = fmaf(c1.w, f0, e.w);
    }
    const float avg = 0.25f * (a0 + a1 + a2 + a3);
#pragma unroll
    for (int k = 0; k < 10; ++k) {
      const float4 h = HQ4[k * 196 + t];
      float a = fmaf(h.x, e.x, fmaf(h.y, e.y, fmaf(h.z, e.z, h.w * e.w)));
      acc[k] = fmaf(WA[k * 196 + t], avg, a);
    }
  }
  if (t >= 196 && t < 232) {
    // ---- feat8 depthwise 8x8 stride 8: one (pos, ch) per thread ----
    const int u = t - 196;
    const int pos = u >> 2, ch = u & 3;
    const int i8 = pos / 3, j8 = pos % 3;
    const float4* w84 = (const float4*)dw8_w;
    float4 a8 = {0.f, 0.f, 0.f, 0.f};
#pragma unroll
    for (int uu = 0; uu < 8; ++uu) {
      const float4 xa = xs4[(8 * i8 + uu) * 7 + 2 * j8];
      const float4 xb = xs4[(8 * i8 + uu) * 7 + 2 * j8 + 1];
      const float4 wa = w84[ch * 16 + uu * 2];
      const float4 wb = w84[ch * 16 + uu * 2 + 1];
      a8.x = fmaf(wa.x, xa.x, a8.x); a8.y = fmaf(wa.y, xa.y, a8.y);
      a8.z = fmaf(wa.z, xa.z, a8.z); a8.w = fmaf(wa.w, xa.w, a8.w);
      a8.x = fmaf(wb.x, xb.x, a8.x); a8.y = fmaf(wb.y, xb.y, a8.y);
      a8.z = fmaf(wb.z, xb.z, a8.z); a8.w = fmaf(wb.w, xb.w, a8.w);
    }
    z8d[u] = a8.x + a8.y + a8.z + a8.w + dw8_b[ch];
  }
  if (t >= 196 && t < 245) {
    // ---- feat4: 4x4 stride-4 dw + 1x1 + relu, dot into acc ----
    const int tt = t - 196;
    const int i = tt / 7, j = tt % 7;
    const float4* w44 = (const float4*)dw4_w;
    float y[4];
#pragma unroll
    for (int c = 0; c < 4; ++c) {
      float4 a4 = {0.f, 0.f, 0.f, 0.f};
#pragma unroll
      for (int u = 0; u < 4; ++u) {
        const float4 xa = xs4[(4 * i + u) * 7 + j];
        const float4 wa = w44[c * 4 + u];
        a4.x = fmaf(wa.x, xa.x, a4.x); a4.y = fmaf(wa.y, xa.y, a4.y);
        a4.z = fmaf(wa.z, xa.z, a4.z); a4.w = fmaf(wa.w, xa.w, a4.w);
      }
      y[c] = a4.x + a4.y + a4.z + a4.w + dw4_b[c];
    }
    float4 z4;
    {
      float z[4];
#pragma unroll
      for (int o = 0; o < 4; ++o) {
        float zz = pw4_b[o];
#pragma unroll
        for (int c = 0; c < 4; ++c) zz = fmaf(pw4_w[o * 4 + c], y[c], zz);
        z[o] = fmaxf(zz, 0.f);
      }
      z4 = {z[0], z[1], z[2], z[3]};
    }
#pragma unroll
    for (int k = 0; k < 10; ++k) {
      const float4 h = H44[k * 49 + tt];
      acc[k] += fmaf(h.x, z4.x, fmaf(h.y, z4.y, fmaf(h.z, z4.z, h.w * z4.w)));
    }
  }
  __syncthreads();

  if (t >= 196 && t < 205) {
    // ---- pw8 + relu + dot into acc ----
    const int p8 = t - 196;
    float yv[4];
#pragma unroll
    for (int c = 0; c < 4; ++c) yv[c] = z8d[p8 * 4 + c];
    float z[4];
#pragma unroll
    for (int o = 0; o < 4; ++o) {
      float zz = pw8_b[o];
#pragma unroll
      for (int c = 0; c < 4; ++c) zz = fmaf(pw8_w[o * 4 + c], yv[c], zz);
      z[o] = fmaxf(zz, 0.f);
    }
#pragma unroll
    for (int k = 0; k < 10; ++k) {
      const float4 h = H84[k * 9 + p8];
      acc[k] += fmaf(h.x, z[0], fmaf(h.y, z[1], fmaf(h.z, z[2], h.w * z[3])));
    }
  }

  // ---- block reduction of acc[10] ----
#pragma unroll
  for (int k = 0; k < 10; ++k) {
#pragma unroll
    for (int off = 32; off > 0; off >>= 1) acc[k] += __shfl_xor(acc[k], off);
  }
  const int lane = t & 63, w = t >> 6;
  if (lane == 0) {
#pragma unroll
    for (int k = 0; k < 10; ++k) red[w * 10 + k] = acc[k];
  }
  __syncthreads();
  if (t == 0) {
    float lg[10], m = -1e30f;
#pragma unroll
    for (int k = 0; k < 10; ++k) {
      lg[k] = red[k] + red[10 + k] + red[20 + k] + red[30 + k] + C10[k];
      m = fmaxf(m, lg[k]);
    }
    float se = 0.f;
#pragma unroll
    for (int k = 0; k < 10; ++k) se += __expf(lg[k] - m);
    const float ls = m + __logf(se);
#pragma unroll
    for (int k = 0; k < 10; ++k) out[b * 10 + k] = lg[k] - ls;
  }
}

extern "C" void kernel_launch(void* const* d_in, const int* in_sizes, int n_in,
                              void* d_out, int out_size, void* d_ws, size_t ws_size,
                              hipStream_t stream) {
  const float* x      = (const float*)d_in[0];
  const float* qp     = (const float*)d_in[1];
  const float* dw4_w  = (const float*)d_in[2];
  const float* dw4_b  = (const float*)d_in[3];
  const float* pw4_w  = (const float*)d_in[4];
  const float* pw4_b  = (const float*)d_in[5];
  const float* dw8_w  = (const float*)d_in[6];
  const float* dw8_b  = (const float*)d_in[7];
  const float* pw8_w  = (const float*)d_in[8];
  const float* pw8_b  = (const float*)d_in[9];
  const float* res_w  = (const float*)d_in[10];
  const float* res_b  = (const float*)d_in[11];
  const float* head_w = (const float*)d_in[12];
  const float* head_b = (const float*)d_in[13];
  float* out = (float*)d_out;
  float* ws = (float*)d_ws;
  const int B = in_sizes[0] / 784;

  hipLaunchKernelGGL(prep_kernel, dim3(11), dim3(256), 0, stream,
                     qp, head_w, res_w, res_b, head_b, ws);
  hipLaunchKernelGGL(qmain_kernel, dim3(B), dim3(256), 0, stream,
                     x, (const float4*)(ws + WS_T),
                     (const float4*)(ws + WS_HQ), ws + WS_WA,
                     (const float4*)(ws + WS_H4), (const float4*)(ws + WS_H8),
                     ws + WS_C10,
                     dw4_w, dw4_b, pw4_w, pw4_b, dw8_w, dw8_b, pw8_w, pw8_b,
                     out);
}

// Round 4
// 35.085 us; speedup vs baseline: 1.5106x; 1.1373x over previous
//
#include <hip/hip_runtime.h>

// ws layout (float offsets)
#define WS_T    0      // 324 floats: trig-basis tensor T[81][4]
#define WS_HQ   512    // 7840: hwq[k][pos] as float4 (quantum head weights)
#define WS_WA   8352   // 1960: wavg[k][pos] (residual-avg head weights)
#define WS_H4   10312  // 1960: hz4[k][p4] as float4
#define WS_H8   12272  // 360:  hz8[k][p8] as float4
#define WS_C10  12632  // 10:   per-class constant (hb + res_b terms)

__device__ __forceinline__ float4 f4fma(const float4 a, const float s, const float4 c) {
  return {fmaf(a.x, s, c.x), fmaf(a.y, s, c.y), fmaf(a.z, s, c.z), fmaf(a.w, s, c.w)};
}
__device__ __forceinline__ float4 f4add(const float4 a, const float4 b) {
  return {a.x + b.x, a.y + b.y, a.z + b.z, a.w + b.w};
}

// ---------------------------------------------------------------------------
// Prep kernel, grid = 11 blocks (unchanged from round 3).
// ---------------------------------------------------------------------------
__global__ __launch_bounds__(256) void prep_kernel(
    const float* __restrict__ qp, const float* __restrict__ hw,
    const float* __restrict__ res_w, const float* __restrict__ res_b,
    const float* __restrict__ hb, float* __restrict__ ws) {
  __shared__ float row[2352];
  __shared__ float cred[4];
  __shared__ float Sr[16][16];
  __shared__ float Si[16][16];
  __shared__ float csc[36], css[36];
  __shared__ float Afs[256][4];
  const int t = threadIdx.x;

  if (blockIdx.x < 10) {
    const int k = blockIdx.x;
    for (int i = t; i < 2352; i += 256) row[i] = hw[k * 2352 + i];
    __syncthreads();
    float cpart = 0.f;
    if (t < 196) {
      const int b12 = t * 12;
      float4 h = {row[b12], row[b12 + 1], row[b12 + 2], row[b12 + 3]};
      ((float4*)(ws + WS_HQ))[k * 196 + t] = h;
      float wa = 0.f;
#pragma unroll
      for (int c = 0; c < 4; ++c) {
        const float s3 = row[b12 + c] + row[b12 + 4 + c] + row[b12 + 8 + c];
        wa += res_w[c] * s3;
        cpart += res_b[c] * s3;
      }
      ws[WS_WA + k * 196 + t] = wa;
    }
    if (t < 49) {
      const int i4 = t / 7, j4 = t % 7;
      float4 s = {0.f, 0.f, 0.f, 0.f};
#pragma unroll
      for (int di = 0; di < 2; ++di)
#pragma unroll
        for (int dj = 0; dj < 2; ++dj) {
          const int pos = (2 * i4 + di) * 14 + 2 * j4 + dj;
          s.x += row[pos * 12 + 4]; s.y += row[pos * 12 + 5];
          s.z += row[pos * 12 + 6]; s.w += row[pos * 12 + 7];
        }
      ((float4*)(ws + WS_H4))[k * 49 + t] = s;
    }
    if (t < 9) {
      const int i8 = t / 3, j8 = t % 3;
      const int pi0 = (i8 == 0) ? 0 : ((i8 == 1) ? 5 : 9);
      const int pi1 = (i8 == 0) ? 5 : ((i8 == 1) ? 9 : 14);
      const int pj0 = (j8 == 0) ? 0 : ((j8 == 1) ? 5 : 9);
      const int pj1 = (j8 == 0) ? 5 : ((j8 == 1) ? 9 : 14);
      float4 s = {0.f, 0.f, 0.f, 0.f};
      for (int pi = pi0; pi < pi1; ++pi)
        for (int pj = pj0; pj < pj1; ++pj) {
          const int pos = pi * 14 + pj;
          s.x += row[pos * 12 + 8]; s.y += row[pos * 12 + 9];
          s.z += row[pos * 12 + 10]; s.w += row[pos * 12 + 11];
        }
      ((float4*)(ws + WS_H8))[k * 9 + t] = s;
    }
#pragma unroll
    for (int off = 32; off > 0; off >>= 1) cpart += __shfl_xor(cpart, off);
    if ((t & 63) == 0) cred[t >> 6] = cpart;
    __syncthreads();
    if (t == 0) ws[WS_C10 + k] = hb[k] + cred[0] + cred[1] + cred[2] + cred[3];
    return;
  }

  // ---- block 10: quantum tensor T ----
  if (t < 36) {
    float th = 0.5f * qp[t];
    csc[t] = cosf(th);
    css[t] = sinf(th);
  }
  Sr[t >> 4][t & 15] = ((t >> 4) == (t & 15)) ? 1.f : 0.f;
  Si[t >> 4][t & 15] = 0.f;
  __syncthreads();

  const int col = t >> 3, pp = t & 7;
  for (int l = 0; l < 3; ++l) {
    for (int q = 0; q < 4; ++q) {
      const int m = 8 >> q;
      for (int r = 0; r < 3; ++r) {
        if (t < 128) {
          const float c = csc[l * 12 + q * 3 + r];
          const float s = css[l * 12 + q * 3 + r];
          const int k = ((pp & ~(m - 1)) << 1) | (pp & (m - 1));
          const int k1 = k | m;
          float a0r = Sr[col][k],  a0i = Si[col][k];
          float a1r = Sr[col][k1], a1i = Si[col][k1];
          float n0r, n0i, n1r, n1i;
          if (r == 0) {         // RX
            n0r = c * a0r + s * a1i;  n0i = c * a0i - s * a1r;
            n1r = c * a1r + s * a0i;  n1i = c * a1i - s * a0r;
          } else if (r == 1) {  // RY
            n0r = c * a0r - s * a1r;  n0i = c * a0i - s * a1i;
            n1r = s * a0r + c * a1r;  n1i = s * a0i + c * a1i;
          } else {              // RZ
            n0r = c * a0r + s * a0i;  n0i = c * a0i - s * a0r;
            n1r = c * a1r - s * a1i;  n1i = c * a1i + s * a1r;
          }
          Sr[col][k] = n0r;  Si[col][k] = n0i;
          Sr[col][k1] = n1r; Si[col][k1] = n1i;
        }
        __syncthreads();
      }
    }
    for (int e = 0; e < 4; ++e) {
      if (t < 64) {
        const int c2 = t >> 2, p2 = t & 3;
        const int mc = 8 >> e;
        const int mt = 8 >> ((e + 1) & 3);
        const int rest = 15 & ~(mc | mt);
        const int rl = rest & (-rest);
        const int rh = rest ^ rl;
        const int k = mc | ((p2 & 1) ? rl : 0) | ((p2 & 2) ? rh : 0);
        const int k1 = k | mt;
        float tr = Sr[c2][k]; Sr[c2][k] = Sr[c2][k1]; Sr[c2][k1] = tr;
        float ti = Si[c2][k]; Si[c2][k] = Si[c2][k1]; Si[c2][k1] = ti;
      }
      __syncthreads();
    }
  }

  {
    const int i = t >> 4, j = t & 15;
    float a0 = 0.f, a1 = 0.f, a2 = 0.f, a3 = 0.f;
    for (int k = 0; k < 16; ++k) {
      float pr = Sr[i][k] * Sr[j][k] + Si[i][k] * Si[j][k];
      a0 += (k & 8) ? -pr : pr;
      a1 += (k & 4) ? -pr : pr;
      a2 += (k & 2) ? -pr : pr;
      a3 += (k & 1) ? -pr : pr;
    }
    Afs[t][0] = a0; Afs[t][1] = a1; Afs[t][2] = a2; Afs[t][3] = a3;
  }
  __syncthreads();

  for (int o = t; o < 324; o += 256) {
    const int mi = o >> 2, q = o & 3;
    const int m0 = mi / 27, m1 = (mi / 9) % 3, m2 = (mi / 3) % 3, m3 = mi % 3;
    const int mm[4] = {m0, m1, m2, m3};
    float acc = 0.f;
    for (int c = 0; c < 16; ++c) {
      int ii = 0, jj = 0; float sg = 1.f;
      for (int qb = 0; qb < 4; ++qb) {
        const int cb = (c >> qb) & 1, bit = 8 >> qb, mq = mm[qb];
        if (mq == 2) { if (cb) ii |= bit; else jj |= bit; }
        else if (cb) { ii |= bit; jj |= bit; if (mq == 1) sg = -sg; }
      }
      acc += sg * Afs[ii * 16 + jj][q];
    }
    ws[WS_T + mi * 4 + q] = acc * 0.0625f;
  }
}

// ---------------------------------------------------------------------------
// Main kernel: one block per image. Role-rotated waves, chunked Horner,
// LDS-transpose logit reduction.
// ---------------------------------------------------------------------------
__global__ __launch_bounds__(256, 4) void qmain_kernel(
    const float* __restrict__ x, const float4* __restrict__ T4,
    const float4* __restrict__ HQ4, const float* __restrict__ WA,
    const float4* __restrict__ H44, const float4* __restrict__ H84,
    const float* __restrict__ C10,
    const float* __restrict__ dw4_w, const float* __restrict__ dw4_b,
    const float* __restrict__ pw4_w, const float* __restrict__ pw4_b,
    const float* __restrict__ dw8_w, const float* __restrict__ dw8_b,
    const float* __restrict__ pw8_w, const float* __restrict__ pw8_b,
    float* __restrict__ out) {
  __shared__ __align__(16) float xs[784];
  __shared__ float accs[10 * 257];  // padded rows: bank-conflict-free
  __shared__ float part[160];       // 10 x 16
  __shared__ float lgs[10];
  const int b = blockIdx.x, t = threadIdx.x;
  // Whole-wave role rotation: the heavy "side" wave lands on a different
  // SIMD for consecutive resident blocks (same-CU blocks differ in b or b>>8).
  const int rot = ((b >> 8) + b) & 3;
  const int vt = (t + (rot << 6)) & 255;
  const float4* xs4 = (const float4*)xs;

  if (t < 196) ((float4*)xs)[t] = ((const float4*)(x + b * 784))[t];
  __syncthreads();

  float acc[10];
#pragma unroll
  for (int k = 0; k < 10; ++k) acc[k] = 0.f;

  if (vt < 196) {
    // ---- quantum feature (chunked trig-basis contraction) ----
    const int pi = vt / 14, pj = vt % 14;
    const int base = (2 * pi) * 28 + 2 * pj;
    const float a0 = xs[base], a1 = xs[base + 1];
    const float a2 = xs[base + 28], a3 = xs[base + 29];
    float c0, s0, c1, s1, c2, s2, c3, s3;
    __sincosf(a0, &s0, &c0);
    __sincosf(a1, &s1, &c1);
    __sincosf(a2, &s2, &c2);
    __sincosf(a3, &s3, &c3);
    float4 ea = {0.f, 0.f, 0.f, 0.f};  // m0 = 1 partial
    float4 eb = {0.f, 0.f, 0.f, 0.f};  // m0 = cos partial
    float4 ec = {0.f, 0.f, 0.f, 0.f};  // m0 = sin partial
#pragma unroll
    for (int g = 0; g < 9; ++g) {      // g = m0*3 + m1
      const float4 t0 = T4[g * 9 + 0], t1 = T4[g * 9 + 1], t2 = T4[g * 9 + 2];
      const float4 t3 = T4[g * 9 + 3], t4 = T4[g * 9 + 4], t5 = T4[g * 9 + 5];
      const float4 t6 = T4[g * 9 + 6], t7 = T4[g * 9 + 7], t8 = T4[g * 9 + 8];
      const float4 u0 = f4fma(t2, s3, f4fma(t1, c3, t0));
      const float4 u1 = f4fma(t5, s3, f4fma(t4, c3, t3));
      const float4 u2 = f4fma(t8, s3, f4fma(t7, c3, t6));
      float4 inner = f4fma(u2, s2, f4fma(u1, c2, u0));
      const int m1 = g % 3;
      if (m1 == 1) inner = {inner.x * c1, inner.y * c1, inner.z * c1, inner.w * c1};
      if (m1 == 2) inner = {inner.x * s1, inner.y * s1, inner.z * s1, inner.w * s1};
      if (g < 3)      ea = f4add(ea, inner);
      else if (g < 6) eb = f4add(eb, inner);
      else            ec = f4add(ec, inner);
    }
    const float4 e = f4fma(ec, s0, f4fma(eb, c0, ea));
    const float avg = 0.25f * (a0 + a1 + a2 + a3);
#pragma unroll
    for (int k = 0; k < 10; ++k) {
      const float4 h = HQ4[k * 196 + vt];
      float a = fmaf(h.x, e.x, fmaf(h.y, e.y, fmaf(h.z, e.z, h.w * e.w)));
      acc[k] = fmaf(WA[k * 196 + vt], avg, a);
    }
  } else {
    const int u = vt - 196;  // 0..59
    if (u < 36) {
      // ---- feat8 depthwise 8x8 stride 8: one (pos, ch) per lane ----
      const int pos = u >> 2, ch = u & 3;
      const int i8 = pos / 3, j8 = pos % 3;
      const float4* w84 = (const float4*)dw8_w;
      float4 a8 = {0.f, 0.f, 0.f, 0.f};
#pragma unroll
      for (int uu = 0; uu < 8; ++uu) {
        const float4 xa = xs4[(8 * i8 + uu) * 7 + 2 * j8];
        const float4 xb = xs4[(8 * i8 + uu) * 7 + 2 * j8 + 1];
        const float4 wa = w84[ch * 16 + uu * 2];
        const float4 wb = w84[ch * 16 + uu * 2 + 1];
        a8.x = fmaf(wa.x, xa.x, a8.x); a8.y = fmaf(wa.y, xa.y, a8.y);
        a8.z = fmaf(wa.z, xa.z, a8.z); a8.w = fmaf(wa.w, xa.w, a8.w);
        a8.x = fmaf(wb.x, xb.x, a8.x); a8.y = fmaf(wb.y, xb.y, a8.y);
        a8.z = fmaf(wb.z, xb.z, a8.z); a8.w = fmaf(wb.w, xb.w, a8.w);
      }
      const float d8 = a8.x + a8.y + a8.z + a8.w + dw8_b[ch];
      // quad-gather the 4 channels to the ch==0 lane (lanes are contiguous
      // within one wave for all rotations: run starts at wave lane 4)
      const float z1 = __shfl_down(d8, 1);
      const float z2 = __shfl_down(d8, 2);
      const float z3 = __shfl_down(d8, 3);
      if (ch == 0) {
        const float yv[4] = {d8, z1, z2, z3};
        float z[4];
#pragma unroll
        for (int o = 0; o < 4; ++o) {
          float zz = pw8_b[o];
#pragma unroll
          for (int c = 0; c < 4; ++c) zz = fmaf(pw8_w[o * 4 + c], yv[c], zz);
          z[o] = fmaxf(zz, 0.f);
        }
#pragma unroll
        for (int k = 0; k < 10; ++k) {
          const float4 h = H84[k * 9 + pos];
          acc[k] += fmaf(h.x, z[0], fmaf(h.y, z[1], fmaf(h.z, z[2], h.w * z[3])));
        }
      }
    }
    if (u < 49) {
      // ---- feat4: 4x4 stride-4 dw + 1x1 + relu, dot into acc ----
      const int i = u / 7, j = u % 7;
      const float4* w44 = (const float4*)dw4_w;
      float y[4];
#pragma unroll
      for (int c = 0; c < 4; ++c) {
        float4 a4 = {0.f, 0.f, 0.f, 0.f};
#pragma unroll
        for (int uu = 0; uu < 4; ++uu) {
          const float4 xa = xs4[(4 * i + uu) * 7 + j];
          const float4 wa = w44[c * 4 + uu];
          a4.x = fmaf(wa.x, xa.x, a4.x); a4.y = fmaf(wa.y, xa.y, a4.y);
          a4.z = fmaf(wa.z, xa.z, a4.z); a4.w = fmaf(wa.w, xa.w, a4.w);
        }
        y[c] = a4.x + a4.y + a4.z + a4.w + dw4_b[c];
      }
      float z[4];
#pragma unroll
      for (int o = 0; o < 4; ++o) {
        float zz = pw4_b[o];
#pragma unroll
        for (int c = 0; c < 4; ++c) zz = fmaf(pw4_w[o * 4 + c], y[c], zz);
        z[o] = fmaxf(zz, 0.f);
      }
#pragma unroll
      for (int k = 0; k < 10; ++k) {
        const float4 h = H44[k * 49 + u];
        acc[k] += fmaf(h.x, z[0], fmaf(h.y, z[1], fmaf(h.z, z[2], h.w * z[3])));
      }
    }
  }

  // ---- LDS-transpose logit reduction ----
#pragma unroll
  for (int k = 0; k < 10; ++k) accs[k * 257 + t] = acc[k];
  __syncthreads();
  if (t < 160) {
    const int k = t >> 4, c = t & 15;
    float s = 0.f;
#pragma unroll
    for (int i = 0; i < 16; ++i) s += accs[k * 257 + c + 16 * i];
    part[k * 16 + c] = s;
  }
  __syncthreads();
  if (t < 10) {
    float lg = C10[t];
#pragma unroll
    for (int c = 0; c < 16; ++c) lg += part[t * 16 + c];
    lgs[t] = lg;
  }
  __syncthreads();
  if (t < 10) {
    float m = lgs[0];
#pragma unroll
    for (int i = 1; i < 10; ++i) m = fmaxf(m, lgs[i]);
    float se = 0.f;
#pragma unroll
    for (int i = 0; i < 10; ++i) se += __expf(lgs[i] - m);
    out[b * 10 + t] = lgs[t] - m - __logf(se);
  }
}

extern "C" void kernel_launch(void* const* d_in, const int* in_sizes, int n_in,
                              void* d_out, int out_size, void* d_ws, size_t ws_size,
                              hipStream_t stream) {
  const float* x      = (const float*)d_in[0];
  const float* qp     = (const float*)d_in[1];
  const float* dw4_w  = (const float*)d_in[2];
  const float* dw4_b  = (const float*)d_in[3];
  const float* pw4_w  = (const float*)d_in[4];
  const float* pw4_b  = (const float*)d_in[5];
  const float* dw8_w  = (const float*)d_in[6];
  const float* dw8_b  = (const float*)d_in[7];
  const float* pw8_w  = (const float*)d_in[8];
  const float* pw8_b  = (const float*)d_in[9];
  const float* res_w  = (const float*)d_in[10];
  const float* res_b  = (const float*)d_in[11];
  const float* head_w = (const float*)d_in[12];
  const float* head_b = (const float*)d_in[13];
  float* out = (float*)d_out;
  float* ws = (float*)d_ws;
  const int B = in_sizes[0] / 784;

  hipLaunchKernelGGL(prep_kernel, dim3(11), dim3(256), 0, stream,
                     qp, head_w, res_w, res_b, head_b, ws);
  hipLaunchKernelGGL(qmain_kernel, dim3(B), dim3(256), 0, stream,
                     x, (const float4*)(ws + WS_T),
                     (const float4*)(ws + WS_HQ), ws + WS_WA,
                     (const float4*)(ws + WS_H4), (const float4*)(ws + WS_H8),
                     ws + WS_C10,
                     dw4_w, dw4_b, pw4_w, pw4_b, dw8_w, dw8_b, pw8_w, pw8_b,
                     out);
}

// Round 5
// 33.857 us; speedup vs baseline: 1.5654x; 1.0363x over previous
//
#include <hip/hip_runtime.h>

// ws layout (float offsets)
#define WS_T    0      // 324 floats: trig-basis tensor T[81][4]
#define WS_HQ   512    // 7840: hwq[k][pos] as float4 (quantum head weights)
#define WS_WA   8352   // 1960: wavg[k][pos] (residual-avg head weights)
#define WS_H4   10312  // 1960: hz4[k][p4] as float4
#define WS_H8   12272  // 360:  hz8[k][p8] as float4
#define WS_C10  12632  // 10:   per-class constant (hb + res_b terms)

__device__ __forceinline__ float4 f4fma(const float4 a, const float s, const float4 c) {
  return {fmaf(a.x, s, c.x), fmaf(a.y, s, c.y), fmaf(a.z, s, c.z), fmaf(a.w, s, c.w)};
}
__device__ __forceinline__ float4 f4fma4(const float4 a, const float4 b, const float4 c) {
  return {fmaf(a.x, b.x, c.x), fmaf(a.y, b.y, c.y), fmaf(a.z, b.z, c.z), fmaf(a.w, b.w, c.w)};
}
__device__ __forceinline__ float hsum4(const float4 a) {
  return a.x + a.y + a.z + a.w;
}

// ---------------------------------------------------------------------------
// Prep kernel, grid = 11 blocks (unchanged from round 4).
// ---------------------------------------------------------------------------
__global__ __launch_bounds__(256) void prep_kernel(
    const float* __restrict__ qp, const float* __restrict__ hw,
    const float* __restrict__ res_w, const float* __restrict__ res_b,
    const float* __restrict__ hb, float* __restrict__ ws) {
  __shared__ float row[2352];
  __shared__ float cred[4];
  __shared__ float Sr[16][16];
  __shared__ float Si[16][16];
  __shared__ float csc[36], css[36];
  __shared__ float Afs[256][4];
  const int t = threadIdx.x;

  if (blockIdx.x < 10) {
    const int k = blockIdx.x;
    for (int i = t; i < 2352; i += 256) row[i] = hw[k * 2352 + i];
    __syncthreads();
    float cpart = 0.f;
    if (t < 196) {
      const int b12 = t * 12;
      float4 h = {row[b12], row[b12 + 1], row[b12 + 2], row[b12 + 3]};
      ((float4*)(ws + WS_HQ))[k * 196 + t] = h;
      float wa = 0.f;
#pragma unroll
      for (int c = 0; c < 4; ++c) {
        const float s3 = row[b12 + c] + row[b12 + 4 + c] + row[b12 + 8 + c];
        wa += res_w[c] * s3;
        cpart += res_b[c] * s3;
      }
      ws[WS_WA + k * 196 + t] = wa;
    }
    if (t < 49) {
      const int i4 = t / 7, j4 = t % 7;
      float4 s = {0.f, 0.f, 0.f, 0.f};
#pragma unroll
      for (int di = 0; di < 2; ++di)
#pragma unroll
        for (int dj = 0; dj < 2; ++dj) {
          const int pos = (2 * i4 + di) * 14 + 2 * j4 + dj;
          s.x += row[pos * 12 + 4]; s.y += row[pos * 12 + 5];
          s.z += row[pos * 12 + 6]; s.w += row[pos * 12 + 7];
        }
      ((float4*)(ws + WS_H4))[k * 49 + t] = s;
    }
    if (t < 9) {
      const int i8 = t / 3, j8 = t % 3;
      const int pi0 = (i8 == 0) ? 0 : ((i8 == 1) ? 5 : 9);
      const int pi1 = (i8 == 0) ? 5 : ((i8 == 1) ? 9 : 14);
      const int pj0 = (j8 == 0) ? 0 : ((j8 == 1) ? 5 : 9);
      const int pj1 = (j8 == 0) ? 5 : ((j8 == 1) ? 9 : 14);
      float4 s = {0.f, 0.f, 0.f, 0.f};
      for (int pi = pi0; pi < pi1; ++pi)
        for (int pj = pj0; pj < pj1; ++pj) {
          const int pos = pi * 14 + pj;
          s.x += row[pos * 12 + 8]; s.y += row[pos * 12 + 9];
          s.z += row[pos * 12 + 10]; s.w += row[pos * 12 + 11];
        }
      ((float4*)(ws + WS_H8))[k * 9 + t] = s;
    }
#pragma unroll
    for (int off = 32; off > 0; off >>= 1) cpart += __shfl_xor(cpart, off);
    if ((t & 63) == 0) cred[t >> 6] = cpart;
    __syncthreads();
    if (t == 0) ws[WS_C10 + k] = hb[k] + cred[0] + cred[1] + cred[2] + cred[3];
    return;
  }

  // ---- block 10: quantum tensor T ----
  if (t < 36) {
    float th = 0.5f * qp[t];
    csc[t] = cosf(th);
    css[t] = sinf(th);
  }
  Sr[t >> 4][t & 15] = ((t >> 4) == (t & 15)) ? 1.f : 0.f;
  Si[t >> 4][t & 15] = 0.f;
  __syncthreads();

  const int col = t >> 3, pp = t & 7;
  for (int l = 0; l < 3; ++l) {
    for (int q = 0; q < 4; ++q) {
      const int m = 8 >> q;
      for (int r = 0; r < 3; ++r) {
        if (t < 128) {
          const float c = csc[l * 12 + q * 3 + r];
          const float s = css[l * 12 + q * 3 + r];
          const int k = ((pp & ~(m - 1)) << 1) | (pp & (m - 1));
          const int k1 = k | m;
          float a0r = Sr[col][k],  a0i = Si[col][k];
          float a1r = Sr[col][k1], a1i = Si[col][k1];
          float n0r, n0i, n1r, n1i;
          if (r == 0) {         // RX
            n0r = c * a0r + s * a1i;  n0i = c * a0i - s * a1r;
            n1r = c * a1r + s * a0i;  n1i = c * a1i - s * a0r;
          } else if (r == 1) {  // RY
            n0r = c * a0r - s * a1r;  n0i = c * a0i - s * a1i;
            n1r = s * a0r + c * a1r;  n1i = s * a0i + c * a1i;
          } else {              // RZ
            n0r = c * a0r + s * a0i;  n0i = c * a0i - s * a0r;
            n1r = c * a1r - s * a1i;  n1i = c * a1i + s * a1r;
          }
          Sr[col][k] = n0r;  Si[col][k] = n0i;
          Sr[col][k1] = n1r; Si[col][k1] = n1i;
        }
        __syncthreads();
      }
    }
    for (int e = 0; e < 4; ++e) {
      if (t < 64) {
        const int c2 = t >> 2, p2 = t & 3;
        const int mc = 8 >> e;
        const int mt = 8 >> ((e + 1) & 3);
        const int rest = 15 & ~(mc | mt);
        const int rl = rest & (-rest);
        const int rh = rest ^ rl;
        const int k = mc | ((p2 & 1) ? rl : 0) | ((p2 & 2) ? rh : 0);
        const int k1 = k | mt;
        float tr = Sr[c2][k]; Sr[c2][k] = Sr[c2][k1]; Sr[c2][k1] = tr;
        float ti = Si[c2][k]; Si[c2][k] = Si[c2][k1]; Si[c2][k1] = ti;
      }
      __syncthreads();
    }
  }

  {
    const int i = t >> 4, j = t & 15;
    float a0 = 0.f, a1 = 0.f, a2 = 0.f, a3 = 0.f;
    for (int k = 0; k < 16; ++k) {
      float pr = Sr[i][k] * Sr[j][k] + Si[i][k] * Si[j][k];
      a0 += (k & 8) ? -pr : pr;
      a1 += (k & 4) ? -pr : pr;
      a2 += (k & 2) ? -pr : pr;
      a3 += (k & 1) ? -pr : pr;
    }
    Afs[t][0] = a0; Afs[t][1] = a1; Afs[t][2] = a2; Afs[t][3] = a3;
  }
  __syncthreads();

  for (int o = t; o < 324; o += 256) {
    const int mi = o >> 2, q = o & 3;
    const int m0 = mi / 27, m1 = (mi / 9) % 3, m2 = (mi / 3) % 3, m3 = mi % 3;
    const int mm[4] = {m0, m1, m2, m3};
    float acc = 0.f;
    for (int c = 0; c < 16; ++c) {
      int ii = 0, jj = 0; float sg = 1.f;
      for (int qb = 0; qb < 4; ++qb) {
        const int cb = (c >> qb) & 1, bit = 8 >> qb, mq = mm[qb];
        if (mq == 2) { if (cb) ii |= bit; else jj |= bit; }
        else if (cb) { ii |= bit; jj |= bit; if (mq == 1) sg = -sg; }
      }
      acc += sg * Afs[ii * 16 + jj][q];
    }
    ws[WS_T + mi * 4 + q] = acc * 0.0625f;
  }
}

// ---------------------------------------------------------------------------
// Main kernel: ONE WAVE PER IMAGE. 4 waves/block, grid B/4 = exactly
// 4 waves/SIMD chip-wide, single generation, no block barriers after staging.
// Rounds 0-2: 64 quantum patches each. Round 3: 4 quantum + feat4 + feat8.
// Logits via 64-lane shfl_xor butterfly; log-softmax in-registers.
// ---------------------------------------------------------------------------
__global__ __launch_bounds__(256, 4) void qmain_kernel(
    const float* __restrict__ x, const float4* __restrict__ T4,
    const float4* __restrict__ HQ4, const float* __restrict__ WA,
    const float4* __restrict__ H44, const float4* __restrict__ H84,
    const float* __restrict__ C10,
    const float* __restrict__ dw4_w, const float* __restrict__ dw4_b,
    const float* __restrict__ pw4_w, const float* __restrict__ pw4_b,
    const float* __restrict__ dw8_w, const float* __restrict__ dw8_b,
    const float* __restrict__ pw8_w, const float* __restrict__ pw8_b,
    float* __restrict__ out, const int B) {
  __shared__ __align__(16) float xs[4 * 792];  // 792 = 784 + 8 pad, 16B-mult
  const int t = threadIdx.x;
  const int w = t >> 6, lane = t & 63;
  const int img = blockIdx.x * 4 + w;
  float* xw = xs + w * 792;
  const float4* xw4 = (const float4*)xw;

  if (img < B) {
    const float4* xg = (const float4*)(x + img * 784);
#pragma unroll
    for (int it = 0; it < 4; ++it) {
      const int idx = it * 64 + lane;
      if (idx < 196) ((float4*)xw)[idx] = xg[idx];
    }
  }
  __syncthreads();  // only cross-wave LDS safety point

  if (img >= B) return;

  float acc[10];
#pragma unroll
  for (int k = 0; k < 10; ++k) acc[k] = 0.f;

#pragma unroll 1
  for (int r = 0; r < 4; ++r) {
    const int p = r * 64 + lane;
    if (p < 196) {
      // ---- quantum feature (chunked trig-basis contraction) + head dot ----
      const int pi = p / 14, pj = p % 14;
      const int base = 56 * pi + 2 * pj;  // even -> 8B aligned
      const float2 a01 = *(const float2*)(xw + base);
      const float2 a23 = *(const float2*)(xw + base + 28);
      const float a0 = a01.x, a1 = a01.y, a2 = a23.x, a3 = a23.y;
      float c0, s0, c1, s1, c2, s2, c3, s3;
      __sincosf(a0, &s0, &c0);
      __sincosf(a1, &s1, &c1);
      __sincosf(a2, &s2, &c2);
      __sincosf(a3, &s3, &c3);
      const float w01[9] = {1.f, c1, s1, c0, c0 * c1, c0 * s1, s0, s0 * c1, s0 * s1};
      float4 e = {0.f, 0.f, 0.f, 0.f};
#pragma unroll
      for (int g = 0; g < 9; ++g) {
        const float4 t0 = T4[g * 9 + 0], t1 = T4[g * 9 + 1], t2 = T4[g * 9 + 2];
        const float4 t3 = T4[g * 9 + 3], t4 = T4[g * 9 + 4], t5 = T4[g * 9 + 5];
        const float4 t6 = T4[g * 9 + 6], t7 = T4[g * 9 + 7], t8 = T4[g * 9 + 8];
        const float4 u0 = f4fma(t2, s3, f4fma(t1, c3, t0));
        const float4 u1 = f4fma(t5, s3, f4fma(t4, c3, t3));
        const float4 u2 = f4fma(t8, s3, f4fma(t7, c3, t6));
        const float4 inner = f4fma(u2, s2, f4fma(u1, c2, u0));
        e = f4fma(inner, w01[g], e);
      }
      const float avg = 0.25f * (a0 + a1 + a2 + a3);
#pragma unroll
      for (int k = 0; k < 10; ++k) {
        const float4 h = HQ4[k * 196 + p];
        acc[k] += fmaf(h.x, e.x, fmaf(h.y, e.y,
                  fmaf(h.z, e.z, fmaf(h.w, e.w, WA[k * 196 + p] * avg))));
      }
    } else {
      const int u = p - 196;  // only reachable at r==3
      if (u < 49) {
        // ---- feat4: 4x4 stride-4 dw + 1x1 + relu + head dot ----
        const int i = u / 7, j = u % 7;
        const float4* w44 = (const float4*)dw4_w;
        float4 q0 = {0.f, 0.f, 0.f, 0.f}, q1 = q0, q2 = q0, q3 = q0;
#pragma unroll
        for (int uu = 0; uu < 4; ++uu) {
          const float4 xa = xw4[(4 * i + uu) * 7 + j];
          q0 = f4fma4(w44[0 + uu], xa, q0);
          q1 = f4fma4(w44[4 + uu], xa, q1);
          q2 = f4fma4(w44[8 + uu], xa, q2);
          q3 = f4fma4(w44[12 + uu], xa, q3);
        }
        const float y0 = hsum4(q0) + dw4_b[0];
        const float y1 = hsum4(q1) + dw4_b[1];
        const float y2 = hsum4(q2) + dw4_b[2];
        const float y3 = hsum4(q3) + dw4_b[3];
        float z[4];
#pragma unroll
        for (int o = 0; o < 4; ++o) {
          float zz = pw4_b[o];
          zz = fmaf(pw4_w[o * 4 + 0], y0, zz);
          zz = fmaf(pw4_w[o * 4 + 1], y1, zz);
          zz = fmaf(pw4_w[o * 4 + 2], y2, zz);
          zz = fmaf(pw4_w[o * 4 + 3], y3, zz);
          z[o] = fmaxf(zz, 0.f);
        }
#pragma unroll
        for (int k = 0; k < 10; ++k) {
          const float4 h = H44[k * 49 + u];
          acc[k] += fmaf(h.x, z[0], fmaf(h.y, z[1], fmaf(h.z, z[2], h.w * z[3])));
        }
      } else if (u < 58) {
        // ---- feat8: 8x8 stride-8 dw (all 4 ch) + 1x1 + relu + head dot ----
        const int pos = u - 49;
        const int i8 = pos / 3, j8 = pos % 3;
        const float4* w84 = (const float4*)dw8_w;
        float4 e0 = {0.f, 0.f, 0.f, 0.f}, e1 = e0, e2 = e0, e3 = e0;
#pragma unroll
        for (int uu = 0; uu < 8; ++uu) {
          const float4 xa = xw4[(8 * i8 + uu) * 7 + 2 * j8];
          const float4 xb = xw4[(8 * i8 + uu) * 7 + 2 * j8 + 1];
          e0 = f4fma4(w84[0 + uu * 2], xa, e0);
          e0 = f4fma4(w84[1 + uu * 2], xb, e0);
          e1 = f4fma4(w84[16 + uu * 2], xa, e1);
          e1 = f4fma4(w84[17 + uu * 2], xb, e1);
          e2 = f4fma4(w84[32 + uu * 2], xa, e2);
          e2 = f4fma4(w84[33 + uu * 2], xb, e2);
          e3 = f4fma4(w84[48 + uu * 2], xa, e3);
          e3 = f4fma4(w84[49 + uu * 2], xb, e3);
        }
        const float d0 = hsum4(e0) + dw8_b[0];
        const float d1 = hsum4(e1) + dw8_b[1];
        const float d2 = hsum4(e2) + dw8_b[2];
        const float d3 = hsum4(e3) + dw8_b[3];
        float z[4];
#pragma unroll
        for (int o = 0; o < 4; ++o) {
          float zz = pw8_b[o];
          zz = fmaf(pw8_w[o * 4 + 0], d0, zz);
          zz = fmaf(pw8_w[o * 4 + 1], d1, zz);
          zz = fmaf(pw8_w[o * 4 + 2], d2, zz);
          zz = fmaf(pw8_w[o * 4 + 3], d3, zz);
          z[o] = fmaxf(zz, 0.f);
        }
#pragma unroll
        for (int k = 0; k < 10; ++k) {
          const float4 h = H84[k * 9 + pos];
          acc[k] += fmaf(h.x, z[0], fmaf(h.y, z[1], fmaf(h.z, z[2], h.w * z[3])));
        }
      }
    }
  }

  // ---- 64-lane butterfly reduction (wave-lockstep, no barrier) ----
#pragma unroll
  for (int k = 0; k < 10; ++k) {
    float v = acc[k];
    v += __shfl_xor(v, 1);
    v += __shfl_xor(v, 2);
    v += __shfl_xor(v, 4);
    v += __shfl_xor(v, 8);
    v += __shfl_xor(v, 16);
    v += __shfl_xor(v, 32);
    acc[k] = v;
  }

  // ---- log-softmax, computed redundantly in all lanes ----
  float lg[10], m = -1e30f;
#pragma unroll
  for (int k = 0; k < 10; ++k) {
    lg[k] = acc[k] + C10[k];
    m = fmaxf(m, lg[k]);
  }
  float se = 0.f;
#pragma unroll
  for (int k = 0; k < 10; ++k) se += __expf(lg[k] - m);
  const float ls = m + __logf(se);
  if (lane < 10) {
    float v = lg[0];
#pragma unroll
    for (int k = 1; k < 10; ++k)
      if (lane == k) v = lg[k];
    out[img * 10 + lane] = v - ls;
  }
}

extern "C" void kernel_launch(void* const* d_in, const int* in_sizes, int n_in,
                              void* d_out, int out_size, void* d_ws, size_t ws_size,
                              hipStream_t stream) {
  const float* x      = (const float*)d_in[0];
  const float* qp     = (const float*)d_in[1];
  const float* dw4_w  = (const float*)d_in[2];
  const float* dw4_b  = (const float*)d_in[3];
  const float* pw4_w  = (const float*)d_in[4];
  const float* pw4_b  = (const float*)d_in[5];
  const float* dw8_w  = (const float*)d_in[6];
  const float* dw8_b  = (const float*)d_in[7];
  const float* pw8_w  = (const float*)d_in[8];
  const float* pw8_b  = (const float*)d_in[9];
  const float* res_w  = (const float*)d_in[10];
  const float* res_b  = (const float*)d_in[11];
  const float* head_w = (const float*)d_in[12];
  const float* head_b = (const float*)d_in[13];
  float* out = (float*)d_out;
  float* ws = (float*)d_ws;
  const int B = in_sizes[0] / 784;

  hipLaunchKernelGGL(prep_kernel, dim3(11), dim3(256), 0, stream,
                     qp, head_w, res_w, res_b, head_b, ws);
  hipLaunchKernelGGL(qmain_kernel, dim3((B + 3) / 4), dim3(256), 0, stream,
                     x, (const float4*)(ws + WS_T),
                     (const float4*)(ws + WS_HQ), ws + WS_WA,
                     (const float4*)(ws + WS_H4), (const float4*)(ws + WS_H8),
                     ws + WS_C10,
                     dw4_w, dw4_b, pw4_w, pw4_b, dw8_w, dw8_b, pw8_w, pw8_b,
                     out, B);
}